// Round 1
// baseline (1392.249 us; speedup 1.0000x reference)
//
#include <hip/hip_runtime.h>
#include <hip/hip_bf16.h>

#define SCAN_B 256

// ---------- preprocessing ----------

__global__ void hist_kernel(const int* __restrict__ edges, int* __restrict__ deg, int e) {
    int i = blockIdx.x * blockDim.x + threadIdx.x;
    if (i < e) atomicAdd(&deg[edges[e + i]], 1);  // dst = edges[1][i]
}

__global__ void scan_pass1(const int* __restrict__ deg, int* __restrict__ partials, int n) {
    __shared__ int sh[SCAN_B];
    int tid = threadIdx.x;
    int i = blockIdx.x * SCAN_B + tid;
    sh[tid] = (i < n) ? deg[i] : 0;
    __syncthreads();
    for (int s = SCAN_B / 2; s > 0; s >>= 1) {
        if (tid < s) sh[tid] += sh[tid + s];
        __syncthreads();
    }
    if (tid == 0) partials[blockIdx.x] = sh[0];
}

__global__ void scan_pass2(int* partials, int nblk) {
    __shared__ int sh[512];
    int tid = threadIdx.x;
    int v = (tid < nblk) ? partials[tid] : 0;
    sh[tid] = v;
    __syncthreads();
    for (int off = 1; off < 512; off <<= 1) {
        int t = (tid >= off) ? sh[tid - off] : 0;
        __syncthreads();
        sh[tid] += t;
        __syncthreads();
    }
    if (tid < nblk) partials[tid] = sh[tid] - v;  // exclusive
}

__global__ void scan_pass3(const int* __restrict__ deg, const int* __restrict__ partials,
                           int* __restrict__ row_off, int* __restrict__ fill_ptr, int n, int e) {
    __shared__ int sh[SCAN_B];
    int tid = threadIdx.x;
    int i = blockIdx.x * SCAN_B + tid;
    int v = (i < n) ? deg[i] : 0;
    sh[tid] = v;
    __syncthreads();
    for (int off = 1; off < SCAN_B; off <<= 1) {
        int t = (tid >= off) ? sh[tid - off] : 0;
        __syncthreads();
        sh[tid] += t;
        __syncthreads();
    }
    if (i < n) {
        int excl = partials[blockIdx.x] + sh[tid] - v;
        row_off[i] = excl;
        fill_ptr[i] = excl;
    }
    if (i == 0) row_off[n] = e;
}

__global__ void fill_kernel(const int* __restrict__ edges, const int* __restrict__ deg,
                            int* __restrict__ fill_ptr, int* __restrict__ csr_src,
                            float* __restrict__ csr_norm, int e) {
    int i = blockIdx.x * blockDim.x + threadIdx.x;
    if (i >= e) return;
    int s = edges[i];
    int d = edges[e + i];
    int pos = atomicAdd(&fill_ptr[d], 1);
    float ds = (float)max(deg[s], 1);
    float dd = (float)max(deg[d], 1);
    csr_src[pos] = s;
    csr_norm[pos] = rsqrtf(ds * dd);
}

// ---------- conv: h_out = 0.9 * A_norm @ h_in + 0.1 * h0 ----------
// one lane per (node, feature); 32 lanes = one node row (128B coalesced gather)

__global__ __launch_bounds__(256) void conv_kernel(
    const float* __restrict__ hin, const float* __restrict__ h0, float* __restrict__ hout,
    const int* __restrict__ row_off, const int* __restrict__ csr_src,
    const float* __restrict__ csr_norm, int n) {
    int gid = blockIdx.x * blockDim.x + threadIdx.x;
    int node = gid >> 5;
    int f = gid & 31;
    if (node >= n) return;
    int j0 = row_off[node];
    int j1 = row_off[node + 1];
    float acc = 0.0f;
    int j = j0;
    // 2-way unroll so the two gathers can be in flight together
    for (; j + 1 < j1; j += 2) {
        int s0 = csr_src[j], s1 = csr_src[j + 1];
        float w0 = csr_norm[j], w1 = csr_norm[j + 1];
        float v0 = hin[s0 * 32 + f];
        float v1 = hin[s1 * 32 + f];
        acc += w0 * v0;
        acc += w1 * v1;
    }
    if (j < j1) {
        acc += csr_norm[j] * hin[csr_src[j] * 32 + f];
    }
    hout[gid] = 0.9f * acc + 0.1f * h0[gid];
}

// ---------- per-(node,feature) MLP ----------
// y[n][f] = b2 + sum_j W2[j] * relu(x[n][f]*W1[0][j] + c[f][j]),
// c[f][j] = b1[j] + emb[f,:] @ W1[1:7, j]

__global__ __launch_bounds__(256) void mlp_kernel(
    const float* __restrict__ hin, float* __restrict__ hout,
    const float* __restrict__ emb,   // [32][6]
    const float* __restrict__ W1,    // [7][9] row-major
    const float* __restrict__ b1,    // [9]
    const float* __restrict__ W2,    // [9]
    const float* __restrict__ b2,    // [1]
    int total) {
    __shared__ float c[32][9];
    __shared__ float w0[9], w2[9];
    __shared__ float b2s;
    int tid = threadIdx.x;
    for (int i = tid; i < 288; i += blockDim.x) {
        int f = i / 9, jj = i % 9;
        float acc = b1[jj];
#pragma unroll
        for (int k = 0; k < 6; ++k) acc += emb[f * 6 + k] * W1[(1 + k) * 9 + jj];
        c[f][jj] = acc;
    }
    if (tid < 9) { w0[tid] = W1[tid]; w2[tid] = W2[tid]; }
    if (tid == 0) b2s = b2[0];
    __syncthreads();
    int gid = blockIdx.x * blockDim.x + tid;
    if (gid >= total) return;
    int f = gid & 31;
    float xv = hin[gid];
    float acc = b2s;
#pragma unroll
    for (int jj = 0; jj < 9; ++jj)
        acc += fmaxf(xv * w0[jj] + c[f][jj], 0.0f) * w2[jj];
    hout[gid] = acc;
}

// ---------- output projection: out = h @ Wout + bout ----------

__global__ __launch_bounds__(256) void out_kernel(
    const float* __restrict__ h, const float* __restrict__ Wout,
    const float* __restrict__ bout, float* __restrict__ out, int n) {
    __shared__ float w[32 * 16];
    __shared__ float bo[16];
    int tid = threadIdx.x;
    for (int i = tid; i < 512; i += blockDim.x) w[i] = Wout[i];
    if (tid < 16) bo[tid] = bout[tid];
    __syncthreads();
    int gid = blockIdx.x * blockDim.x + tid;
    int node = gid >> 4;
    int cls = gid & 15;
    if (node >= n) return;
    const float* hr = h + node * 32;
    float acc = bo[cls];
#pragma unroll
    for (int f = 0; f < 32; ++f) acc += hr[f] * w[f * 16 + cls];
    out[gid] = acc;
}

extern "C" void kernel_launch(void* const* d_in, const int* in_sizes, int n_in,
                              void* d_out, int out_size, void* d_ws, size_t ws_size,
                              hipStream_t stream) {
    const float* x    = (const float*)d_in[0];
    const int* edges  = (const int*)d_in[1];
    const float* emb  = (const float*)d_in[2];
    const float* W1   = (const float*)d_in[3];
    const float* b1   = (const float*)d_in[4];
    const float* W2   = (const float*)d_in[5];
    const float* b2   = (const float*)d_in[6];
    const float* Wout = (const float*)d_in[7];
    const float* bout = (const float*)d_in[8];
    float* out        = (float*)d_out;

    const int N = in_sizes[0] / 32;
    const int E = in_sizes[1] / 2;

    size_t off = 0;
    auto walloc = [&](size_t bytes) {
        void* p = (char*)d_ws + off;
        off += (bytes + 255) & ~(size_t)255;
        return p;
    };
    int*   deg      = (int*)  walloc((size_t)N * 4);
    int*   row_off  = (int*)  walloc((size_t)(N + 1) * 4);
    int*   fill_ptr = (int*)  walloc((size_t)N * 4);
    int*   partials = (int*)  walloc(512 * 4);
    int*   csr_src  = (int*)  walloc((size_t)E * 4);
    float* csr_norm = (float*)walloc((size_t)E * 4);
    float* bufA     = (float*)walloc((size_t)N * 32 * 4);
    float* bufB     = (float*)walloc((size_t)N * 32 * 4);
    float* bufC     = (float*)walloc((size_t)N * 32 * 4);

    const int nblk_scan = (N + SCAN_B - 1) / SCAN_B;

    hipMemsetAsync(deg, 0, (size_t)N * 4, stream);
    hist_kernel<<<(E + 255) / 256, 256, 0, stream>>>(edges, deg, E);
    scan_pass1<<<nblk_scan, SCAN_B, 0, stream>>>(deg, partials, N);
    scan_pass2<<<1, 512, 0, stream>>>(partials, nblk_scan);
    scan_pass3<<<nblk_scan, SCAN_B, 0, stream>>>(deg, partials, row_off, fill_ptr, N, E);
    fill_kernel<<<(E + 255) / 256, 256, 0, stream>>>(edges, deg, fill_ptr, csr_src, csr_norm, E);

    const int conv_blocks = (N * 32 + 255) / 256;

    // diffuse #1 (h0 = x)
    {
        const float* hin = x;
        for (int it = 0; it < 10; ++it) {
            float* ho = (it & 1) ? bufB : bufA;
            conv_kernel<<<conv_blocks, 256, 0, stream>>>(hin, x, ho, row_off, csr_src, csr_norm, N);
            hin = ho;
        }
    }
    // per-(node,feature) MLP: bufB -> bufC
    mlp_kernel<<<conv_blocks, 256, 0, stream>>>(bufB, bufC, emb, W1, b1, W2, b2, N * 32);

    // diffuse #2 (h0 = bufC)
    {
        const float* hin = bufC;
        for (int it = 0; it < 10; ++it) {
            float* ho = (it & 1) ? bufB : bufA;
            conv_kernel<<<conv_blocks, 256, 0, stream>>>(hin, bufC, ho, row_off, csr_src, csr_norm, N);
            hin = ho;
        }
    }
    // out = bufB @ Wout + bout
    out_kernel<<<(N * 16 + 255) / 256, 256, 0, stream>>>(bufB, Wout, bout, out, N);
}

// Round 2
// 942.047 us; speedup vs baseline: 1.4779x; 1.4779x over previous
//
#include <hip/hip_runtime.h>
#include <hip/hip_bf16.h>

#define SCAN_B 256

// ---------- preprocessing ----------

__global__ void hist_kernel(const int* __restrict__ edges, int* __restrict__ deg, int e) {
    int i = blockIdx.x * blockDim.x + threadIdx.x;
    if (i < e) atomicAdd(&deg[edges[e + i]], 1);  // dst = edges[1][i]
}

__global__ void scan_pass1(const int* __restrict__ deg, int* __restrict__ partials, int n) {
    __shared__ int sh[SCAN_B];
    int tid = threadIdx.x;
    int i = blockIdx.x * SCAN_B + tid;
    sh[tid] = (i < n) ? deg[i] : 0;
    __syncthreads();
    for (int s = SCAN_B / 2; s > 0; s >>= 1) {
        if (tid < s) sh[tid] += sh[tid + s];
        __syncthreads();
    }
    if (tid == 0) partials[blockIdx.x] = sh[0];
}

__global__ void scan_pass2(int* partials, int nblk) {
    __shared__ int sh[512];
    int tid = threadIdx.x;
    int v = (tid < nblk) ? partials[tid] : 0;
    sh[tid] = v;
    __syncthreads();
    for (int off = 1; off < 512; off <<= 1) {
        int t = (tid >= off) ? sh[tid - off] : 0;
        __syncthreads();
        sh[tid] += t;
        __syncthreads();
    }
    if (tid < nblk) partials[tid] = sh[tid] - v;  // exclusive
}

__global__ void scan_pass3(const int* __restrict__ deg, const int* __restrict__ partials,
                           int* __restrict__ row_off, int* __restrict__ fill_ptr, int n, int e) {
    __shared__ int sh[SCAN_B];
    int tid = threadIdx.x;
    int i = blockIdx.x * SCAN_B + tid;
    int v = (i < n) ? deg[i] : 0;
    sh[tid] = v;
    __syncthreads();
    for (int off = 1; off < SCAN_B; off <<= 1) {
        int t = (tid >= off) ? sh[tid - off] : 0;
        __syncthreads();
        sh[tid] += t;
        __syncthreads();
    }
    if (i < n) {
        int excl = partials[blockIdx.x] + sh[tid] - v;
        row_off[i] = excl;
        fill_ptr[i] = excl;
    }
    if (i == 0) row_off[n] = e;
}

// packed CSR entry: .x = src node, .y = bitcast(norm). One 8B scattered store
// instead of two 4B stores to separate arrays (halves write amplification).
__global__ void fill_kernel(const int* __restrict__ edges, const int* __restrict__ deg,
                            int* __restrict__ fill_ptr, int2* __restrict__ csr_ent, int e) {
    int i = blockIdx.x * blockDim.x + threadIdx.x;
    if (i >= e) return;
    int s = edges[i];
    int d = edges[e + i];
    int pos = atomicAdd(&fill_ptr[d], 1);
    float ds = (float)max(deg[s], 1);
    float dd = (float)max(deg[d], 1);
    int2 ent;
    ent.x = s;
    ent.y = __float_as_int(rsqrtf(ds * dd));
    csr_ent[pos] = ent;
}

// ---------- conv: h_out = 0.9 * A_norm @ h_in + 0.1 * h0 ----------
// 8 lanes per node, each lane owns a float4 (4 features). Row gather:
// 8 lanes x 16B = 128B contiguous per node. Edge metadata: one int2 load,
// broadcast across the node's 8 lanes.

__global__ __launch_bounds__(256) void conv_kernel(
    const float4* __restrict__ hin4, const float4* __restrict__ h04,
    float4* __restrict__ hout4, const int* __restrict__ row_off,
    const int2* __restrict__ csr_ent, int n) {
    int gid = blockIdx.x * blockDim.x + threadIdx.x;
    int node = gid >> 3;
    int q = gid & 7;
    if (node >= n) return;
    int j0 = row_off[node];
    int j1 = row_off[node + 1];
    float ax0 = 0.f, ay0 = 0.f, az0 = 0.f, aw0 = 0.f;
    float ax1 = 0.f, ay1 = 0.f, az1 = 0.f, aw1 = 0.f;
    int j = j0;
    for (; j + 1 < j1; j += 2) {
        int2 e0 = csr_ent[j];
        int2 e1 = csr_ent[j + 1];
        float w0 = __int_as_float(e0.y);
        float w1 = __int_as_float(e1.y);
        float4 v0 = hin4[(size_t)e0.x * 8 + q];
        float4 v1 = hin4[(size_t)e1.x * 8 + q];
        ax0 += w0 * v0.x; ay0 += w0 * v0.y; az0 += w0 * v0.z; aw0 += w0 * v0.w;
        ax1 += w1 * v1.x; ay1 += w1 * v1.y; az1 += w1 * v1.z; aw1 += w1 * v1.w;
    }
    if (j < j1) {
        int2 e0 = csr_ent[j];
        float w0 = __int_as_float(e0.y);
        float4 v0 = hin4[(size_t)e0.x * 8 + q];
        ax0 += w0 * v0.x; ay0 += w0 * v0.y; az0 += w0 * v0.z; aw0 += w0 * v0.w;
    }
    float4 h0v = h04[gid];
    float4 r;
    r.x = 0.9f * (ax0 + ax1) + 0.1f * h0v.x;
    r.y = 0.9f * (ay0 + ay1) + 0.1f * h0v.y;
    r.z = 0.9f * (az0 + az1) + 0.1f * h0v.z;
    r.w = 0.9f * (aw0 + aw1) + 0.1f * h0v.w;
    hout4[gid] = r;
}

// ---------- per-(node,feature) MLP ----------
// y[n][f] = b2 + sum_j W2[j] * relu(x[n][f]*W1[0][j] + c[f][j]),
// c[f][j] = b1[j] + emb[f,:] @ W1[1:7, j]

__global__ __launch_bounds__(256) void mlp_kernel(
    const float* __restrict__ hin, float* __restrict__ hout,
    const float* __restrict__ emb,   // [32][6]
    const float* __restrict__ W1,    // [7][9] row-major
    const float* __restrict__ b1,    // [9]
    const float* __restrict__ W2,    // [9]
    const float* __restrict__ b2,    // [1]
    int total) {
    __shared__ float c[32][9];
    __shared__ float w0[9], w2[9];
    __shared__ float b2s;
    int tid = threadIdx.x;
    for (int i = tid; i < 288; i += blockDim.x) {
        int f = i / 9, jj = i % 9;
        float acc = b1[jj];
#pragma unroll
        for (int k = 0; k < 6; ++k) acc += emb[f * 6 + k] * W1[(1 + k) * 9 + jj];
        c[f][jj] = acc;
    }
    if (tid < 9) { w0[tid] = W1[tid]; w2[tid] = W2[tid]; }
    if (tid == 0) b2s = b2[0];
    __syncthreads();
    int gid = blockIdx.x * blockDim.x + tid;
    if (gid >= total) return;
    int f = gid & 31;
    float xv = hin[gid];
    float acc = b2s;
#pragma unroll
    for (int jj = 0; jj < 9; ++jj)
        acc += fmaxf(xv * w0[jj] + c[f][jj], 0.0f) * w2[jj];
    hout[gid] = acc;
}

// ---------- output projection: out = h @ Wout + bout ----------

__global__ __launch_bounds__(256) void out_kernel(
    const float* __restrict__ h, const float* __restrict__ Wout,
    const float* __restrict__ bout, float* __restrict__ out, int n) {
    __shared__ float w[32 * 16];
    __shared__ float bo[16];
    int tid = threadIdx.x;
    for (int i = tid; i < 512; i += blockDim.x) w[i] = Wout[i];
    if (tid < 16) bo[tid] = bout[tid];
    __syncthreads();
    int gid = blockIdx.x * blockDim.x + tid;
    int node = gid >> 4;
    int cls = gid & 15;
    if (node >= n) return;
    const float* hr = h + node * 32;
    float acc = bo[cls];
#pragma unroll
    for (int f = 0; f < 32; ++f) acc += hr[f] * w[f * 16 + cls];
    out[gid] = acc;
}

extern "C" void kernel_launch(void* const* d_in, const int* in_sizes, int n_in,
                              void* d_out, int out_size, void* d_ws, size_t ws_size,
                              hipStream_t stream) {
    const float* x    = (const float*)d_in[0];
    const int* edges  = (const int*)d_in[1];
    const float* emb  = (const float*)d_in[2];
    const float* W1   = (const float*)d_in[3];
    const float* b1   = (const float*)d_in[4];
    const float* W2   = (const float*)d_in[5];
    const float* b2   = (const float*)d_in[6];
    const float* Wout = (const float*)d_in[7];
    const float* bout = (const float*)d_in[8];
    float* out        = (float*)d_out;

    const int N = in_sizes[0] / 32;
    const int E = in_sizes[1] / 2;

    size_t off = 0;
    auto walloc = [&](size_t bytes) {
        void* p = (char*)d_ws + off;
        off += (bytes + 255) & ~(size_t)255;
        return p;
    };
    int*   deg      = (int*)  walloc((size_t)N * 4);
    int*   row_off  = (int*)  walloc((size_t)(N + 1) * 4);
    int*   fill_ptr = (int*)  walloc((size_t)N * 4);
    int*   partials = (int*)  walloc(512 * 4);
    int2*  csr_ent  = (int2*) walloc((size_t)E * 8);
    float* bufA     = (float*)walloc((size_t)N * 32 * 4);
    float* bufB     = (float*)walloc((size_t)N * 32 * 4);
    float* bufC     = (float*)walloc((size_t)N * 32 * 4);

    const int nblk_scan = (N + SCAN_B - 1) / SCAN_B;

    hipMemsetAsync(deg, 0, (size_t)N * 4, stream);
    hist_kernel<<<(E + 255) / 256, 256, 0, stream>>>(edges, deg, E);
    scan_pass1<<<nblk_scan, SCAN_B, 0, stream>>>(deg, partials, N);
    scan_pass2<<<1, 512, 0, stream>>>(partials, nblk_scan);
    scan_pass3<<<nblk_scan, SCAN_B, 0, stream>>>(deg, partials, row_off, fill_ptr, N, E);
    fill_kernel<<<(E + 255) / 256, 256, 0, stream>>>(edges, deg, fill_ptr, csr_ent, E);

    const int conv_blocks = (N * 8 + 255) / 256;
    const int elem_blocks = (N * 32 + 255) / 256;

    // diffuse #1 (h0 = x)
    {
        const float4* hin = (const float4*)x;
        for (int it = 0; it < 10; ++it) {
            float4* ho = (float4*)((it & 1) ? bufB : bufA);
            conv_kernel<<<conv_blocks, 256, 0, stream>>>(hin, (const float4*)x, ho,
                                                         row_off, csr_ent, N);
            hin = ho;
        }
    }
    // per-(node,feature) MLP: bufB -> bufC
    mlp_kernel<<<elem_blocks, 256, 0, stream>>>(bufB, bufC, emb, W1, b1, W2, b2, N * 32);

    // diffuse #2 (h0 = bufC)
    {
        const float4* hin = (const float4*)bufC;
        for (int it = 0; it < 10; ++it) {
            float4* ho = (float4*)((it & 1) ? bufB : bufA);
            conv_kernel<<<conv_blocks, 256, 0, stream>>>(hin, (const float4*)bufC, ho,
                                                         row_off, csr_ent, N);
            hin = ho;
        }
    }
    // out = bufB @ Wout + bout
    out_kernel<<<(N * 16 + 255) / 256, 256, 0, stream>>>(bufB, Wout, bout, out, N);
}